// Round 11
// baseline (164.242 us; speedup 1.0000x reference)
//
#include <hip/hip_runtime.h>
#include <hip/hip_cooperative_groups.h>
#include <stdint.h>

namespace cg = cooperative_groups;

#define M_ROWS 8192
#define NCLUST 512
#define KDIM   2048

#define BM 128
#define BN 128
#define BKB 128      // K-step in BYTES (fp8) = 128 K-elements
#define KSPLIT 2
#define NKT (KDIM / KSPLIT / BKB)   // 8 K-steps per block

typedef __attribute__((ext_vector_type(4))) int   i32x4;
typedef __attribute__((ext_vector_type(8))) int   i32x8;
typedef __attribute__((ext_vector_type(4))) float f32x4;
typedef __attribute__((ext_vector_type(8))) unsigned short u16x8;

// round-to-nearest-even f32 -> bf16 (bit pattern)
__device__ __forceinline__ unsigned short f2bf(float f) {
    unsigned u = __float_as_uint(f);
    u += 0x7FFFu + ((u >> 16) & 1u);
    return (unsigned short)(u >> 16);
}
__device__ __forceinline__ float bf2f(unsigned short h) {
    return __uint_as_float(((unsigned)h) << 16);
}

__device__ __forceinline__ void gload_lds16(const void* g, void* l) {
    __builtin_amdgcn_global_load_lds(
        (const __attribute__((address_space(1))) void*)g,
        (__attribute__((address_space(3))) void*)l,
        16, 0, 0);
}

// ---------------------------------------------------------------------------
// Kernel 1: f32 -> fp8 e4m3 + per-row sum of squares (from ORIGINAL f32).
// Rows 0..8191 = z, 8192..8703 = centroids. One wave per row. Zeroes colsum
// (must happen every call: harness does not re-poison between replays).
// ---------------------------------------------------------------------------
__global__ __launch_bounds__(256) void k_convert(
    const float* __restrict__ z, const float* __restrict__ cent,
    unsigned char* __restrict__ zb, unsigned char* __restrict__ cb,
    float* __restrict__ zsq, float* __restrict__ csq,
    float* __restrict__ colsum)
{
    int w = threadIdx.x >> 6, lane = threadIdx.x & 63;
    int row = blockIdx.x * 4 + w;  // 0..8703

    const float* src;
    unsigned char* dst;
    float* nrm;
    int r;
    if (row < M_ROWS) { src = z + (size_t)row * KDIM; dst = zb + (size_t)row * KDIM; nrm = zsq; r = row; }
    else              { r = row - M_ROWS; src = cent + (size_t)r * KDIM; dst = cb + (size_t)r * KDIM; nrm = csq; }

    float s = 0.f;
    #pragma unroll
    for (int it = 0; it < KDIM / 256; ++it) {
        int idx = it * 256 + lane * 4;
        float4 v = *(const float4*)(src + idx);
        s += v.x * v.x + v.y * v.y + v.z * v.z + v.w * v.w;
        int p = __builtin_amdgcn_cvt_pk_fp8_f32(v.x, v.y, 0, 0);   // bytes 0,1
        p     = __builtin_amdgcn_cvt_pk_fp8_f32(v.z, v.w, p, 1);   // bytes 2,3
        *(int*)(dst + idx) = p;
    }
    #pragma unroll
    for (int off = 32; off; off >>= 1) s += __shfl_down(s, off);
    if (lane == 0) nrm[r] = s;

    if (blockIdx.x == 0) {
        colsum[threadIdx.x] = 0.f;
        colsum[threadIdx.x + 256] = 0.f;
    }
}

// ---------------------------------------------------------------------------
// Kernel 2: split-K fp8 MFMA partial GEMM (R10's best verified config).
// 128x128 tile, K-step 128 fp8 elements, 4 waves (2x2, acc[4][4]), KSPLIT=2,
// grid 512 -> 2 blocks/CU (LDS 64 KiB).
// XCD decode: by&7 = wgid&7 -> all 8 blocks sharing an A-panel on one XCD.
// LDS swizzle (both-sides involution): phys 16B slot p at row r holds
// logical p ^ (r&7); pre-swizzled global source, same XOR on ds_read.
// ---------------------------------------------------------------------------
__global__ __launch_bounds__(256) void k_gemm_part(
    const unsigned char* __restrict__ zb, const unsigned char* __restrict__ cb,
    unsigned short* __restrict__ parts)   // [KSPLIT][M_ROWS][NCLUST] bf16
{
    __shared__ unsigned char As[2][BM * BKB];   // 16 KiB x2
    __shared__ unsigned char Bs[2][BN * BKB];   // 16 KiB x2

    const int wgid = blockIdx.x;            // 0..511
    const int inner = wgid >> 3;            // 0..63
    const int bx  = inner & 3;              // N-tile 0..3
    const int bz  = (inner >> 2) & 1;       // K-chunk 0..1
    const int by  = ((inner >> 3) << 3) | (wgid & 7);   // M-tile 0..63
    const int bRow = by * BM;
    const int bCol = bx * BN;
    const size_t kb0 = (size_t)bz * (KDIM / KSPLIT);    // byte offset in K

    const int w    = threadIdx.x >> 6, lane = threadIdx.x & 63;
    const int wr   = w >> 1,  wc   = w & 1;

    f32x4 acc[4][4] = {};

    const int srow = lane >> 3;
    const int scol = ((lane & 7) ^ srow) * 16;
    const unsigned char* gA = zb + (size_t)(bRow + srow) * KDIM + kb0 + scol;
    const unsigned char* gB = cb + (size_t)(bCol + srow) * KDIM + kb0 + scol;

    auto stage = [&](int buf, int kt) {
        const int kb = kt * BKB;
        #pragma unroll
        for (int j = 0; j < 4; ++j) {
            const int g = w * 4 + j;   // 8-row group 0..15
            gload_lds16(gA + (size_t)(g * 8) * KDIM + kb, &As[buf][g * 1024]);
            gload_lds16(gB + (size_t)(g * 8) * KDIM + kb, &Bs[buf][g * 1024]);
        }
    };

    const int arowb = wr * 64 + (lane & 15);
    const int bcolb = wc * 64 + (lane & 15);
    const int s     = lane >> 4;       // K 32-byte block 0..3
    const int r7    = lane & 7;
    const int sc    = 0x7F7F7F7F;      // e8m0 scale 127 = 2^0 per byte

    auto compute = [&](int buf) {
        const unsigned char* A0 = &As[buf][0];
        const unsigned char* B0 = &Bs[buf][0];
        i32x8 af[4], bfr[4];
        #pragma unroll
        for (int i = 0; i < 4; ++i) {
            const int row = arowb + i * 16;
            const i32x4 lo = *(const i32x4*)&A0[row * BKB + ((2 * s) ^ r7) * 16];
            const i32x4 hi = *(const i32x4*)&A0[row * BKB + ((2 * s + 1) ^ r7) * 16];
            af[i][0] = lo[0]; af[i][1] = lo[1]; af[i][2] = lo[2]; af[i][3] = lo[3];
            af[i][4] = hi[0]; af[i][5] = hi[1]; af[i][6] = hi[2]; af[i][7] = hi[3];
        }
        #pragma unroll
        for (int j = 0; j < 4; ++j) {
            const int row = bcolb + j * 16;
            const i32x4 lo = *(const i32x4*)&B0[row * BKB + ((2 * s) ^ r7) * 16];
            const i32x4 hi = *(const i32x4*)&B0[row * BKB + ((2 * s + 1) ^ r7) * 16];
            bfr[j][0] = lo[0]; bfr[j][1] = lo[1]; bfr[j][2] = lo[2]; bfr[j][3] = lo[3];
            bfr[j][4] = hi[0]; bfr[j][5] = hi[1]; bfr[j][6] = hi[2]; bfr[j][7] = hi[3];
        }
        #pragma unroll
        for (int i = 0; i < 4; ++i)
            #pragma unroll
            for (int j = 0; j < 4; ++j)
                acc[i][j] = __builtin_amdgcn_mfma_scale_f32_16x16x128_f8f6f4(
                    af[i], bfr[j], acc[i][j], 0, 0, 0, sc, 0, sc);
    };

    stage(0, 0);
    __syncthreads();
    int buf = 0;
    for (int kt = 0; kt < NKT - 1; ++kt) {
        stage(buf ^ 1, kt + 1);
        compute(buf);
        __syncthreads();
        buf ^= 1;
    }
    compute(buf);

    unsigned short* dst = parts + (size_t)bz * M_ROWS * NCLUST;
    const int col0 = bCol + wc * 64 + (lane & 15);
    const int row0 = bRow + wr * 64 + (lane >> 4) * 4;
    #pragma unroll
    for (int j = 0; j < 4; ++j) {
        const int col = col0 + j * 16;
        #pragma unroll
        for (int i = 0; i < 4; ++i)
            #pragma unroll
            for (int r = 0; r < 4; ++r)
                dst[(size_t)(row0 + i * 16 + r) * NCLUST + col] = f2bf(acc[i][j][r]);
    }
}

// ---------------------------------------------------------------------------
// Kernel 3 (COOPERATIVE): fused Q + P.
// 512 blocks x 256 threads (2/CU, co-resident); block owns 16 rows (wave w
// handles rows rbase + w + 4*rr, rr=0..3; lane covers cols lane*8..+7).
// Phase A: combine 2 bf16 partials -> Q (normalized, written), q kept in
//   registers; LDS-reduce per-block col partials -> device-scope atomicAdd
//   (proven cross-XCD coherent).
// grid.sync(); reload colsum once per block via agent-scope atomic loads
//   (per-XCD L2 non-coherence, G16) into LDS.
// Phase B: P = rownorm(q^2 / colsum) from registers.
// ---------------------------------------------------------------------------
__global__ __launch_bounds__(256) void k_qp_fused(
    const unsigned short* __restrict__ parts,
    const float* __restrict__ zsq, const float* __restrict__ csq,
    float* __restrict__ Q, float* __restrict__ P,
    float* __restrict__ colsum)
{
    cg::grid_group grid = cg::this_grid();
    __shared__ float red[4][NCLUST];
    __shared__ float cls[NCLUST];

    const int tid = threadIdx.x, w = tid >> 6, lane = tid & 63;
    const size_t PSTR = (size_t)M_ROWS * NCLUST;
    const int rbase = blockIdx.x * 16;

    float cs8[8];
    {
        float4 c0 = *(const float4*)(csq + lane * 8);
        float4 c1 = *(const float4*)(csq + lane * 8 + 4);
        cs8[0] = c0.x; cs8[1] = c0.y; cs8[2] = c0.z; cs8[3] = c0.w;
        cs8[4] = c1.x; cs8[5] = c1.y; cs8[6] = c1.z; cs8[7] = c1.w;
    }

    float q[4][8];
    float ca[8] = {0, 0, 0, 0, 0, 0, 0, 0};

    #pragma unroll
    for (int rr = 0; rr < 4; ++rr) {
        const int row = rbase + w + rr * 4;
        const size_t off = (size_t)row * NCLUST + lane * 8;
        float x[8];
        {
            u16x8 v0 = *(const u16x8*)(parts + off);
            u16x8 v1 = *(const u16x8*)(parts + PSTR + off);
            #pragma unroll
            for (int k = 0; k < 8; ++k) x[k] = bf2f(v0[k]) + bf2f(v1[k]);
        }
        const float zr = zsq[row];
        float sum = 0.f;
        #pragma unroll
        for (int k = 0; k < 8; ++k) {
            q[rr][k] = 1.0f / (1.0f + sqrtf(fmaxf(zr + cs8[k] - 2.0f * x[k], 0.0f)));
            sum += q[rr][k];
        }
        #pragma unroll
        for (int o = 32; o; o >>= 1) sum += __shfl_down(sum, o);
        sum = __shfl(sum, 0);
        const float inv = 1.0f / sum;
        float4 q0, q1;
        #pragma unroll
        for (int k = 0; k < 8; ++k) q[rr][k] *= inv;
        q0.x = q[rr][0]; q0.y = q[rr][1]; q0.z = q[rr][2]; q0.w = q[rr][3];
        q1.x = q[rr][4]; q1.y = q[rr][5]; q1.z = q[rr][6]; q1.w = q[rr][7];
        *(float4*)(Q + off)     = q0;
        *(float4*)(Q + off + 4) = q1;
        #pragma unroll
        for (int k = 0; k < 8; ++k) ca[k] += q[rr][k];
    }
    #pragma unroll
    for (int c = 0; c < 8; ++c) red[w][lane * 8 + c] = ca[c];
    __syncthreads();
    {
        const float t0 = red[0][tid] + red[1][tid] + red[2][tid] + red[3][tid];
        const float t1 = red[0][tid + 256] + red[1][tid + 256] + red[2][tid + 256] + red[3][tid + 256];
        atomicAdd(&colsum[tid], t0);          // device-scope, cross-XCD coherent
        atomicAdd(&colsum[tid + 256], t1);
    }
    __threadfence();
    grid.sync();

    // reload colsum coherently (agent-scope loads bypass stale L1/L2 copies)
    cls[tid]       = __hip_atomic_load(&colsum[tid],       __ATOMIC_RELAXED, __HIP_MEMORY_SCOPE_AGENT);
    cls[tid + 256] = __hip_atomic_load(&colsum[tid + 256], __ATOMIC_RELAXED, __HIP_MEMORY_SCOPE_AGENT);
    __syncthreads();

    float ci8[8];
    #pragma unroll
    for (int k = 0; k < 8; ++k) ci8[k] = 1.0f / cls[lane * 8 + k];

    #pragma unroll
    for (int rr = 0; rr < 4; ++rr) {
        const int row = rbase + w + rr * 4;
        float p[8];
        float sum = 0.f;
        #pragma unroll
        for (int k = 0; k < 8; ++k) {
            p[k] = q[rr][k] * q[rr][k] * ci8[k];
            sum += p[k];
        }
        #pragma unroll
        for (int o = 32; o; o >>= 1) sum += __shfl_down(sum, o);
        sum = __shfl(sum, 0);
        const float inv = 1.0f / sum;
        float4 p0, p1;
        p0.x = p[0] * inv; p0.y = p[1] * inv; p0.z = p[2] * inv; p0.w = p[3] * inv;
        p1.x = p[4] * inv; p1.y = p[5] * inv; p1.z = p[6] * inv; p1.w = p[7] * inv;
        const size_t off = (size_t)row * NCLUST + lane * 8;
        *(float4*)(P + off)     = p0;
        *(float4*)(P + off + 4) = p1;
    }
}

// ---------------------------------------------------------------------------
// Fallback kernels (R10-proven) if cooperative launch is unavailable.
// ---------------------------------------------------------------------------
__global__ __launch_bounds__(256) void k_q_norm(
    const unsigned short* __restrict__ parts,
    const float* __restrict__ zsq, const float* __restrict__ csq,
    float* __restrict__ Q, float* __restrict__ colsum)
{
    __shared__ float red[4][NCLUST];
    const int tid = threadIdx.x, w = tid >> 6, lane = tid & 63;
    const size_t PSTR = (size_t)M_ROWS * NCLUST;
    float ca[8] = {0, 0, 0, 0, 0, 0, 0, 0};
    const int rbase = blockIdx.x * 32;

    float cs[8];
    {
        float4 c0 = *(const float4*)(csq + lane * 8);
        float4 c1 = *(const float4*)(csq + lane * 8 + 4);
        cs[0] = c0.x; cs[1] = c0.y; cs[2] = c0.z; cs[3] = c0.w;
        cs[4] = c1.x; cs[5] = c1.y; cs[6] = c1.z; cs[7] = c1.w;
    }

    for (int rr = 0; rr < 8; ++rr) {
        const int row = rbase + w + rr * 4;
        const size_t off = (size_t)row * NCLUST + lane * 8;
        float x[8];
        {
            u16x8 v0 = *(const u16x8*)(parts + off);
            u16x8 v1 = *(const u16x8*)(parts + PSTR + off);
            #pragma unroll
            for (int k = 0; k < 8; ++k) x[k] = bf2f(v0[k]) + bf2f(v1[k]);
        }
        const float zr = zsq[row];
        float q[8];
        float sum = 0.f;
        #pragma unroll
        for (int k = 0; k < 8; ++k) {
            q[k] = 1.0f / (1.0f + sqrtf(fmaxf(zr + cs[k] - 2.0f * x[k], 0.0f)));
            sum += q[k];
        }
        #pragma unroll
        for (int o = 32; o; o >>= 1) sum += __shfl_down(sum, o);
        sum = __shfl(sum, 0);
        const float inv = 1.0f / sum;
        float4 q0, q1;
        q0.x = q[0] * inv; q0.y = q[1] * inv; q0.z = q[2] * inv; q0.w = q[3] * inv;
        q1.x = q[4] * inv; q1.y = q[5] * inv; q1.z = q[6] * inv; q1.w = q[7] * inv;
        *(float4*)(Q + off)     = q0;
        *(float4*)(Q + off + 4) = q1;
        ca[0] += q0.x; ca[1] += q0.y; ca[2] += q0.z; ca[3] += q0.w;
        ca[4] += q1.x; ca[5] += q1.y; ca[6] += q1.z; ca[7] += q1.w;
    }
    #pragma unroll
    for (int c = 0; c < 8; ++c) red[w][lane * 8 + c] = ca[c];
    __syncthreads();
    const float t0 = red[0][tid] + red[1][tid] + red[2][tid] + red[3][tid];
    const float t1 = red[0][tid + 256] + red[1][tid + 256] + red[2][tid + 256] + red[3][tid + 256];
    atomicAdd(&colsum[tid], t0);
    atomicAdd(&colsum[tid + 256], t1);
}

__global__ __launch_bounds__(256) void k_p(
    const float* __restrict__ Q, const float* __restrict__ colsum,
    float* __restrict__ P)
{
    const int w = threadIdx.x >> 6, lane = threadIdx.x & 63;
    const int row = blockIdx.x * 4 + w;
    const float* qp = Q + (size_t)row * NCLUST;
    float4 q0 = *(const float4*)(qp + lane * 4);
    float4 q1 = *(const float4*)(qp + 256 + lane * 4);
    float4 c0 = *(const float4*)(colsum + lane * 4);
    float4 c1 = *(const float4*)(colsum + 256 + lane * 4);
    float4 p0, p1;
    p0.x = q0.x * q0.x / c0.x; p0.y = q0.y * q0.y / c0.y;
    p0.z = q0.z * q0.z / c0.z; p0.w = q0.w * q0.w / c0.w;
    p1.x = q1.x * q1.x / c1.x; p1.y = q1.y * q1.y / c1.y;
    p1.z = q1.z * q1.z / c1.z; p1.w = q1.w * q1.w / c1.w;
    float s = p0.x + p0.y + p0.z + p0.w + p1.x + p1.y + p1.z + p1.w;
    #pragma unroll
    for (int off = 32; off; off >>= 1) s += __shfl_down(s, off);
    s = __shfl(s, 0);
    const float inv = 1.0f / s;
    p0.x *= inv; p0.y *= inv; p0.z *= inv; p0.w *= inv;
    p1.x *= inv; p1.y *= inv; p1.z *= inv; p1.w *= inv;
    float* op = P + (size_t)row * NCLUST;
    *(float4*)(op + lane * 4) = p0;
    *(float4*)(op + 256 + lane * 4) = p1;
}

extern "C" void kernel_launch(void* const* d_in, const int* in_sizes, int n_in,
                              void* d_out, int out_size, void* d_ws, size_t ws_size,
                              hipStream_t stream) {
    const float* z    = (const float*)d_in[0];
    const float* cent = (const float*)d_in[1];
    float* out = (float*)d_out;

    // workspace layout (~35 MiB; ws >= 69 MiB proven empirically in R3)
    char* ws = (char*)d_ws;
    unsigned char* zb = (unsigned char*)ws;                 // 16 MiB fp8
    unsigned char* cb = (unsigned char*)(ws + 16777216);    // 1 MiB fp8
    float* zsq    = (float*)(ws + 17825792);                // 32 KiB
    float* csq    = (float*)(ws + 17858560);                // 2 KiB
    float* colsum = (float*)(ws + 17860608);                // 2 KiB
    unsigned short* parts = (unsigned short*)(ws + 18874368); // 2 x 8 MiB bf16

    float* Q = out;                                  // (8192, 512)
    float* P = out + (size_t)M_ROWS * NCLUST;        // (8192, 512)

    k_convert<<<dim3((M_ROWS + NCLUST) / 4), dim3(256), 0, stream>>>(
        z, cent, zb, cb, zsq, csq, colsum);

    // grid 512 (XCD-aware decode inside) -> 2 blocks/CU, 4 waves each
    k_gemm_part<<<dim3(512), dim3(256), 0, stream>>>(zb, cb, parts);

    // fused Q+P (cooperative, grid-sync); fallback to two-kernel path
    {
        const unsigned short* parts_ = parts;
        const float* zsq_ = zsq; const float* csq_ = csq;
        float* Q_ = Q; float* P_ = P; float* colsum_ = colsum;
        void* args[] = { (void*)&parts_, (void*)&zsq_, (void*)&csq_,
                         (void*)&Q_, (void*)&P_, (void*)&colsum_ };
        hipError_t err = hipLaunchCooperativeKernel(
            (const void*)k_qp_fused, dim3(M_ROWS / 16), dim3(256),
            args, 0, stream);
        if (err != hipSuccess) {
            (void)hipGetLastError();   // clear sticky error
            k_q_norm<<<dim3(M_ROWS / 32), dim3(256), 0, stream>>>(
                parts, zsq, csq, Q, colsum);
            k_p<<<dim3(M_ROWS / 4), dim3(256), 0, stream>>>(Q, colsum, P);
        }
    }
}

// Round 12
// 61.094 us; speedup vs baseline: 2.6884x; 2.6884x over previous
//
#include <hip/hip_runtime.h>
#include <stdint.h>

#define M_ROWS 8192
#define NCLUST 512
#define KDIM   2048

#define BM 128
#define BN 128
#define BKB 128      // K-step in BYTES (fp8) = 128 K-elements
#define KSPLIT 2
#define NKT (KDIM / KSPLIT / BKB)   // 8 K-steps per block

typedef __attribute__((ext_vector_type(4))) int   i32x4;
typedef __attribute__((ext_vector_type(8))) int   i32x8;
typedef __attribute__((ext_vector_type(4))) float f32x4;
typedef __attribute__((ext_vector_type(8))) unsigned short u16x8;

// round-to-nearest-even f32 -> bf16 (bit pattern)
__device__ __forceinline__ unsigned short f2bf(float f) {
    unsigned u = __float_as_uint(f);
    u += 0x7FFFu + ((u >> 16) & 1u);
    return (unsigned short)(u >> 16);
}
__device__ __forceinline__ float bf2f(unsigned short h) {
    return __uint_as_float(((unsigned)h) << 16);
}

__device__ __forceinline__ void gload_lds16(const void* g, void* l) {
    __builtin_amdgcn_global_load_lds(
        (const __attribute__((address_space(1))) void*)g,
        (__attribute__((address_space(3))) void*)l,
        16, 0, 0);
}

// ---------------------------------------------------------------------------
// Kernel 1: f32 -> fp8 e4m3 + per-row sum of squares (from ORIGINAL f32).
// Rows 0..8191 = z, 8192..8703 = centroids. One wave per row. Zeroes colsum
// (must happen every call: harness does not re-poison between replays).
// ---------------------------------------------------------------------------
__global__ __launch_bounds__(256) void k_convert(
    const float* __restrict__ z, const float* __restrict__ cent,
    unsigned char* __restrict__ zb, unsigned char* __restrict__ cb,
    float* __restrict__ zsq, float* __restrict__ csq,
    float* __restrict__ colsum)
{
    int w = threadIdx.x >> 6, lane = threadIdx.x & 63;
    int row = blockIdx.x * 4 + w;  // 0..8703

    const float* src;
    unsigned char* dst;
    float* nrm;
    int r;
    if (row < M_ROWS) { src = z + (size_t)row * KDIM; dst = zb + (size_t)row * KDIM; nrm = zsq; r = row; }
    else              { r = row - M_ROWS; src = cent + (size_t)r * KDIM; dst = cb + (size_t)r * KDIM; nrm = csq; }

    float s = 0.f;
    #pragma unroll
    for (int it = 0; it < KDIM / 256; ++it) {
        int idx = it * 256 + lane * 4;
        float4 v = *(const float4*)(src + idx);
        s += v.x * v.x + v.y * v.y + v.z * v.z + v.w * v.w;
        int p = __builtin_amdgcn_cvt_pk_fp8_f32(v.x, v.y, 0, 0);   // bytes 0,1
        p     = __builtin_amdgcn_cvt_pk_fp8_f32(v.z, v.w, p, 1);   // bytes 2,3
        *(int*)(dst + idx) = p;
    }
    #pragma unroll
    for (int off = 32; off; off >>= 1) s += __shfl_down(s, off);
    if (lane == 0) nrm[r] = s;

    if (blockIdx.x == 0) {
        colsum[threadIdx.x] = 0.f;
        colsum[threadIdx.x + 256] = 0.f;
    }
}

// ---------------------------------------------------------------------------
// Kernel 2: split-K fp8 MFMA partial GEMM.  R10's proven structure (128x128
// tile, K-step 128 fp8 elems, KSPLIT=2, grid 512 -> 2 blocks/CU, XCD-aware
// decode, both-sides LDS swizzle) but with 8 WAVES (512 threads) instead of
// 4: wave grid 2Mx4N, wave-tile 64x32 (acc[4][2]), staging 2A+2B issues per
// wave.  Same LDS (64 KiB) -> still 2 blocks/CU, now 16 waves/CU (4/SIMD)
// to cover the per-K-step vmcnt drain (m97's regime had ~12 waves/CU).
// ---------------------------------------------------------------------------
__global__ __launch_bounds__(512) void k_gemm_part(
    const unsigned char* __restrict__ zb, const unsigned char* __restrict__ cb,
    unsigned short* __restrict__ parts)   // [KSPLIT][M_ROWS][NCLUST] bf16
{
    __shared__ unsigned char As[2][BM * BKB];   // 16 KiB x2
    __shared__ unsigned char Bs[2][BN * BKB];   // 16 KiB x2

    // XCD-aware decode (bijective): by&7 = wgid&7 -> A-panel sharers on 1 XCD
    const int wgid = blockIdx.x;            // 0..511
    const int inner = wgid >> 3;            // 0..63
    const int bx  = inner & 3;              // N-tile 0..3
    const int bz  = (inner >> 2) & 1;       // K-chunk 0..1
    const int by  = ((inner >> 3) << 3) | (wgid & 7);   // M-tile 0..63
    const int bRow = by * BM;
    const int bCol = bx * BN;
    const size_t kb0 = (size_t)bz * (KDIM / KSPLIT);    // byte offset in K

    const int w    = threadIdx.x >> 6, lane = threadIdx.x & 63;
    const int wr   = w >> 2,  wc   = w & 3;   // 2x4 wave grid

    f32x4 acc[4][2] = {};

    // staging: 1 issue = 1 KiB = 8 rows x 128B; 16 groups per matrix;
    // wave w covers groups {2w, 2w+1} for A and B.
    const int srow = lane >> 3;
    const int scol = ((lane & 7) ^ srow) * 16;
    const unsigned char* gA = zb + (size_t)(bRow + srow) * KDIM + kb0 + scol;
    const unsigned char* gB = cb + (size_t)(bCol + srow) * KDIM + kb0 + scol;

    auto stage = [&](int buf, int kt) {
        const int kb = kt * BKB;
        #pragma unroll
        for (int j = 0; j < 2; ++j) {
            const int g = w * 2 + j;   // 8-row group 0..15
            gload_lds16(gA + (size_t)(g * 8) * KDIM + kb, &As[buf][g * 1024]);
            gload_lds16(gB + (size_t)(g * 8) * KDIM + kb, &Bs[buf][g * 1024]);
        }
    };

    const int arowb = wr * 64 + (lane & 15);
    const int bcolb = wc * 32 + (lane & 15);
    const int s     = lane >> 4;       // K 32-byte block 0..3
    const int r7    = lane & 7;
    const int sc    = 0x7F7F7F7F;      // e8m0 scale 127 = 2^0 per byte

    auto compute = [&](int buf) {
        const unsigned char* A0 = &As[buf][0];
        const unsigned char* B0 = &Bs[buf][0];
        i32x8 af[4], bfr[2];
        #pragma unroll
        for (int i = 0; i < 4; ++i) {
            const int row = arowb + i * 16;
            const i32x4 lo = *(const i32x4*)&A0[row * BKB + ((2 * s) ^ r7) * 16];
            const i32x4 hi = *(const i32x4*)&A0[row * BKB + ((2 * s + 1) ^ r7) * 16];
            af[i][0] = lo[0]; af[i][1] = lo[1]; af[i][2] = lo[2]; af[i][3] = lo[3];
            af[i][4] = hi[0]; af[i][5] = hi[1]; af[i][6] = hi[2]; af[i][7] = hi[3];
        }
        #pragma unroll
        for (int j = 0; j < 2; ++j) {
            const int row = bcolb + j * 16;
            const i32x4 lo = *(const i32x4*)&B0[row * BKB + ((2 * s) ^ r7) * 16];
            const i32x4 hi = *(const i32x4*)&B0[row * BKB + ((2 * s + 1) ^ r7) * 16];
            bfr[j][0] = lo[0]; bfr[j][1] = lo[1]; bfr[j][2] = lo[2]; bfr[j][3] = lo[3];
            bfr[j][4] = hi[0]; bfr[j][5] = hi[1]; bfr[j][6] = hi[2]; bfr[j][7] = hi[3];
        }
        #pragma unroll
        for (int i = 0; i < 4; ++i)
            #pragma unroll
            for (int j = 0; j < 2; ++j)
                acc[i][j] = __builtin_amdgcn_mfma_scale_f32_16x16x128_f8f6f4(
                    af[i], bfr[j], acc[i][j], 0, 0, 0, sc, 0, sc);
    };

    stage(0, 0);
    __syncthreads();
    int buf = 0;
    for (int kt = 0; kt < NKT - 1; ++kt) {
        stage(buf ^ 1, kt + 1);
        compute(buf);
        __syncthreads();
        buf ^= 1;
    }
    compute(buf);

    unsigned short* dst = parts + (size_t)bz * M_ROWS * NCLUST;
    // C/D frag mapping: col=lane&15, row=(lane>>4)*4+reg (shape-determined)
    const int col0 = bCol + wc * 32 + (lane & 15);
    const int row0 = bRow + wr * 64 + (lane >> 4) * 4;
    #pragma unroll
    for (int j = 0; j < 2; ++j) {
        const int col = col0 + j * 16;
        #pragma unroll
        for (int i = 0; i < 4; ++i)
            #pragma unroll
            for (int r = 0; r < 4; ++r)
                dst[(size_t)(row0 + i * 16 + r) * NCLUST + col] = f2bf(acc[i][j][r]);
    }
}

// ---------------------------------------------------------------------------
// Kernel 3: combine 2 bf16 partials -> Q = 1/(1+sqrt(max(zsq+csq-2*cross,0))),
// row-normalize, column-sum (LDS reduce -> atomics).  32 rows/block, one
// wave per row, lane covers cols lane*8..+7.  (R10-proven)
// ---------------------------------------------------------------------------
__global__ __launch_bounds__(256) void k_q_norm(
    const unsigned short* __restrict__ parts,
    const float* __restrict__ zsq, const float* __restrict__ csq,
    float* __restrict__ Q, float* __restrict__ colsum)
{
    __shared__ float red[4][NCLUST];
    const int tid = threadIdx.x, w = tid >> 6, lane = tid & 63;
    const size_t PSTR = (size_t)M_ROWS * NCLUST;
    float ca[8] = {0, 0, 0, 0, 0, 0, 0, 0};
    const int rbase = blockIdx.x * 32;

    float cs[8];
    {
        float4 c0 = *(const float4*)(csq + lane * 8);
        float4 c1 = *(const float4*)(csq + lane * 8 + 4);
        cs[0] = c0.x; cs[1] = c0.y; cs[2] = c0.z; cs[3] = c0.w;
        cs[4] = c1.x; cs[5] = c1.y; cs[6] = c1.z; cs[7] = c1.w;
    }

    for (int rr = 0; rr < 8; ++rr) {
        const int row = rbase + w + rr * 4;
        const size_t off = (size_t)row * NCLUST + lane * 8;
        float x[8];
        {
            u16x8 v0 = *(const u16x8*)(parts + off);
            u16x8 v1 = *(const u16x8*)(parts + PSTR + off);
            #pragma unroll
            for (int k = 0; k < 8; ++k) x[k] = bf2f(v0[k]) + bf2f(v1[k]);
        }
        const float zr = zsq[row];
        float q[8];
        float sum = 0.f;
        #pragma unroll
        for (int k = 0; k < 8; ++k) {
            q[k] = 1.0f / (1.0f + sqrtf(fmaxf(zr + cs[k] - 2.0f * x[k], 0.0f)));
            sum += q[k];
        }
        #pragma unroll
        for (int o = 32; o; o >>= 1) sum += __shfl_down(sum, o);
        sum = __shfl(sum, 0);
        const float inv = 1.0f / sum;
        float4 q0, q1;
        q0.x = q[0] * inv; q0.y = q[1] * inv; q0.z = q[2] * inv; q0.w = q[3] * inv;
        q1.x = q[4] * inv; q1.y = q[5] * inv; q1.z = q[6] * inv; q1.w = q[7] * inv;
        *(float4*)(Q + off)     = q0;
        *(float4*)(Q + off + 4) = q1;
        ca[0] += q0.x; ca[1] += q0.y; ca[2] += q0.z; ca[3] += q0.w;
        ca[4] += q1.x; ca[5] += q1.y; ca[6] += q1.z; ca[7] += q1.w;
    }
    #pragma unroll
    for (int c = 0; c < 8; ++c) red[w][lane * 8 + c] = ca[c];
    __syncthreads();
    const float t0 = red[0][tid] + red[1][tid] + red[2][tid] + red[3][tid];
    const float t1 = red[0][tid + 256] + red[1][tid + 256] + red[2][tid + 256] + red[3][tid + 256];
    atomicAdd(&colsum[tid], t0);
    atomicAdd(&colsum[tid + 256], t1);
}

// ---------------------------------------------------------------------------
// Kernel 4: P = rownorm(Q^2 / colsum). One wave per row.  (R10-proven)
// ---------------------------------------------------------------------------
__global__ __launch_bounds__(256) void k_p(
    const float* __restrict__ Q, const float* __restrict__ colsum,
    float* __restrict__ P)
{
    const int w = threadIdx.x >> 6, lane = threadIdx.x & 63;
    const int row = blockIdx.x * 4 + w;
    const float* qp = Q + (size_t)row * NCLUST;
    float4 q0 = *(const float4*)(qp + lane * 4);
    float4 q1 = *(const float4*)(qp + 256 + lane * 4);
    float4 c0 = *(const float4*)(colsum + lane * 4);
    float4 c1 = *(const float4*)(colsum + 256 + lane * 4);
    float4 p0, p1;
    p0.x = q0.x * q0.x / c0.x; p0.y = q0.y * q0.y / c0.y;
    p0.z = q0.z * q0.z / c0.z; p0.w = q0.w * q0.w / c0.w;
    p1.x = q1.x * q1.x / c1.x; p1.y = q1.y * q1.y / c1.y;
    p1.z = q1.z * q1.z / c1.z; p1.w = q1.w * q1.w / c1.w;
    float s = p0.x + p0.y + p0.z + p0.w + p1.x + p1.y + p1.z + p1.w;
    #pragma unroll
    for (int off = 32; off; off >>= 1) s += __shfl_down(s, off);
    s = __shfl(s, 0);
    const float inv = 1.0f / s;
    p0.x *= inv; p0.y *= inv; p0.z *= inv; p0.w *= inv;
    p1.x *= inv; p1.y *= inv; p1.z *= inv; p1.w *= inv;
    float* op = P + (size_t)row * NCLUST;
    *(float4*)(op + lane * 4) = p0;
    *(float4*)(op + 256 + lane * 4) = p1;
}

extern "C" void kernel_launch(void* const* d_in, const int* in_sizes, int n_in,
                              void* d_out, int out_size, void* d_ws, size_t ws_size,
                              hipStream_t stream) {
    const float* z    = (const float*)d_in[0];
    const float* cent = (const float*)d_in[1];
    float* out = (float*)d_out;

    // workspace layout (~35 MiB; ws >= 69 MiB proven empirically in R3)
    char* ws = (char*)d_ws;
    unsigned char* zb = (unsigned char*)ws;                 // 16 MiB fp8
    unsigned char* cb = (unsigned char*)(ws + 16777216);    // 1 MiB fp8
    float* zsq    = (float*)(ws + 17825792);                // 32 KiB
    float* csq    = (float*)(ws + 17858560);                // 2 KiB
    float* colsum = (float*)(ws + 17860608);                // 2 KiB
    unsigned short* parts = (unsigned short*)(ws + 18874368); // 2 x 8 MiB bf16

    float* Q = out;                                  // (8192, 512)
    float* P = out + (size_t)M_ROWS * NCLUST;        // (8192, 512)

    k_convert<<<dim3((M_ROWS + NCLUST) / 4), dim3(256), 0, stream>>>(
        z, cent, zb, cb, zsq, csq, colsum);

    // grid 512 (XCD-aware decode inside) -> 2 blocks/CU, 8 waves each
    k_gemm_part<<<dim3(512), dim3(512), 0, stream>>>(zb, cb, parts);

    k_q_norm<<<dim3(M_ROWS / 32), dim3(256), 0, stream>>>(
        parts, zsq, csq, Q, colsum);

    k_p<<<dim3(M_ROWS / 4), dim3(256), 0, stream>>>(Q, colsum, P);
}

// Round 13
// 56.935 us; speedup vs baseline: 2.8847x; 1.0731x over previous
//
#include <hip/hip_runtime.h>
#include <stdint.h>

#define M_ROWS 8192
#define NCLUST 512
#define KDIM   2048

#define BM 128
#define BN 128
#define BKB 128      // K-step in BYTES (fp8) = 128 K-elements
#define KSPLIT 2
#define NKT (KDIM / KSPLIT / BKB)   // 8 K-steps per block

typedef __attribute__((ext_vector_type(4))) int   i32x4;
typedef __attribute__((ext_vector_type(8))) int   i32x8;
typedef __attribute__((ext_vector_type(4))) float f32x4;
typedef __attribute__((ext_vector_type(8))) unsigned short u16x8;

// round-to-nearest-even f32 -> bf16 (bit pattern)
__device__ __forceinline__ unsigned short f2bf(float f) {
    unsigned u = __float_as_uint(f);
    u += 0x7FFFu + ((u >> 16) & 1u);
    return (unsigned short)(u >> 16);
}
__device__ __forceinline__ float bf2f(unsigned short h) {
    return __uint_as_float(((unsigned)h) << 16);
}

__device__ __forceinline__ void gload_lds16(const void* g, void* l) {
    __builtin_amdgcn_global_load_lds(
        (const __attribute__((address_space(1))) void*)g,
        (__attribute__((address_space(3))) void*)l,
        16, 0, 0);
}

// ---------------------------------------------------------------------------
// Kernel 1: f32 -> fp8 e4m3 + per-row sum of squares (from ORIGINAL f32).
// Rows 0..8191 = z, 8192..8703 = centroids. One wave per row. Zeroes colsum
// (must happen every call: harness does not re-poison between replays).
// ---------------------------------------------------------------------------
__global__ __launch_bounds__(256) void k_convert(
    const float* __restrict__ z, const float* __restrict__ cent,
    unsigned char* __restrict__ zb, unsigned char* __restrict__ cb,
    float* __restrict__ zsq, float* __restrict__ csq,
    float* __restrict__ colsum)
{
    int w = threadIdx.x >> 6, lane = threadIdx.x & 63;
    int row = blockIdx.x * 4 + w;  // 0..8703

    const float* src;
    unsigned char* dst;
    float* nrm;
    int r;
    if (row < M_ROWS) { src = z + (size_t)row * KDIM; dst = zb + (size_t)row * KDIM; nrm = zsq; r = row; }
    else              { r = row - M_ROWS; src = cent + (size_t)r * KDIM; dst = cb + (size_t)r * KDIM; nrm = csq; }

    float s = 0.f;
    #pragma unroll
    for (int it = 0; it < KDIM / 256; ++it) {
        int idx = it * 256 + lane * 4;
        float4 v = *(const float4*)(src + idx);
        s += v.x * v.x + v.y * v.y + v.z * v.z + v.w * v.w;
        int p = __builtin_amdgcn_cvt_pk_fp8_f32(v.x, v.y, 0, 0);   // bytes 0,1
        p     = __builtin_amdgcn_cvt_pk_fp8_f32(v.z, v.w, p, 1);   // bytes 2,3
        *(int*)(dst + idx) = p;
    }
    #pragma unroll
    for (int off = 32; off; off >>= 1) s += __shfl_down(s, off);
    if (lane == 0) nrm[r] = s;

    if (blockIdx.x == 0) {
        colsum[threadIdx.x] = 0.f;
        colsum[threadIdx.x + 256] = 0.f;
    }
}

// ---------------------------------------------------------------------------
// Kernel 2: split-K fp8 MFMA partial GEMM (R10's best-measured config).
// 128x128 tile, K-step 128 fp8 elements, 4 waves (2x2, acc[4][4]), KSPLIT=2,
// grid 512 -> 2 blocks/CU (LDS 64 KiB).
// XCD decode: by&7 = wgid&7 -> all 8 blocks sharing an A-panel on one XCD.
// LDS swizzle (both-sides involution): phys 16B slot p at row r holds
// logical p ^ (r&7); pre-swizzled global source, same XOR on ds_read.
// ---------------------------------------------------------------------------
__global__ __launch_bounds__(256) void k_gemm_part(
    const unsigned char* __restrict__ zb, const unsigned char* __restrict__ cb,
    unsigned short* __restrict__ parts)   // [KSPLIT][M_ROWS][NCLUST] bf16
{
    __shared__ unsigned char As[2][BM * BKB];   // 16 KiB x2
    __shared__ unsigned char Bs[2][BN * BKB];   // 16 KiB x2

    const int wgid = blockIdx.x;            // 0..511
    const int inner = wgid >> 3;            // 0..63
    const int bx  = inner & 3;              // N-tile 0..3
    const int bz  = (inner >> 2) & 1;       // K-chunk 0..1
    const int by  = ((inner >> 3) << 3) | (wgid & 7);   // M-tile 0..63
    const int bRow = by * BM;
    const int bCol = bx * BN;
    const size_t kb0 = (size_t)bz * (KDIM / KSPLIT);    // byte offset in K

    const int w    = threadIdx.x >> 6, lane = threadIdx.x & 63;
    const int wr   = w >> 1,  wc   = w & 1;

    f32x4 acc[4][4] = {};

    const int srow = lane >> 3;
    const int scol = ((lane & 7) ^ srow) * 16;
    const unsigned char* gA = zb + (size_t)(bRow + srow) * KDIM + kb0 + scol;
    const unsigned char* gB = cb + (size_t)(bCol + srow) * KDIM + kb0 + scol;

    auto stage = [&](int buf, int kt) {
        const int kb = kt * BKB;
        #pragma unroll
        for (int j = 0; j < 4; ++j) {
            const int g = w * 4 + j;   // 8-row group 0..15
            gload_lds16(gA + (size_t)(g * 8) * KDIM + kb, &As[buf][g * 1024]);
            gload_lds16(gB + (size_t)(g * 8) * KDIM + kb, &Bs[buf][g * 1024]);
        }
    };

    const int arowb = wr * 64 + (lane & 15);
    const int bcolb = wc * 64 + (lane & 15);
    const int s     = lane >> 4;       // K 32-byte block 0..3
    const int r7    = lane & 7;
    const int sc    = 0x7F7F7F7F;      // e8m0 scale 127 = 2^0 per byte

    auto compute = [&](int buf) {
        const unsigned char* A0 = &As[buf][0];
        const unsigned char* B0 = &Bs[buf][0];
        i32x8 af[4], bfr[4];
        #pragma unroll
        for (int i = 0; i < 4; ++i) {
            const int row = arowb + i * 16;
            const i32x4 lo = *(const i32x4*)&A0[row * BKB + ((2 * s) ^ r7) * 16];
            const i32x4 hi = *(const i32x4*)&A0[row * BKB + ((2 * s + 1) ^ r7) * 16];
            af[i][0] = lo[0]; af[i][1] = lo[1]; af[i][2] = lo[2]; af[i][3] = lo[3];
            af[i][4] = hi[0]; af[i][5] = hi[1]; af[i][6] = hi[2]; af[i][7] = hi[3];
        }
        #pragma unroll
        for (int j = 0; j < 4; ++j) {
            const int row = bcolb + j * 16;
            const i32x4 lo = *(const i32x4*)&B0[row * BKB + ((2 * s) ^ r7) * 16];
            const i32x4 hi = *(const i32x4*)&B0[row * BKB + ((2 * s + 1) ^ r7) * 16];
            bfr[j][0] = lo[0]; bfr[j][1] = lo[1]; bfr[j][2] = lo[2]; bfr[j][3] = lo[3];
            bfr[j][4] = hi[0]; bfr[j][5] = hi[1]; bfr[j][6] = hi[2]; bfr[j][7] = hi[3];
        }
        #pragma unroll
        for (int i = 0; i < 4; ++i)
            #pragma unroll
            for (int j = 0; j < 4; ++j)
                acc[i][j] = __builtin_amdgcn_mfma_scale_f32_16x16x128_f8f6f4(
                    af[i], bfr[j], acc[i][j], 0, 0, 0, sc, 0, sc);
    };

    stage(0, 0);
    __syncthreads();
    int buf = 0;
    for (int kt = 0; kt < NKT - 1; ++kt) {
        stage(buf ^ 1, kt + 1);
        compute(buf);
        __syncthreads();
        buf ^= 1;
    }
    compute(buf);

    unsigned short* dst = parts + (size_t)bz * M_ROWS * NCLUST;
    // C/D frag mapping: col=lane&15, row=(lane>>4)*4+reg (shape-determined)
    const int col0 = bCol + wc * 64 + (lane & 15);
    const int row0 = bRow + wr * 64 + (lane >> 4) * 4;
    #pragma unroll
    for (int j = 0; j < 4; ++j) {
        const int col = col0 + j * 16;
        #pragma unroll
        for (int i = 0; i < 4; ++i)
            #pragma unroll
            for (int r = 0; r < 4; ++r)
                dst[(size_t)(row0 + i * 16 + r) * NCLUST + col] = f2bf(acc[i][j][r]);
    }
}

// ---------------------------------------------------------------------------
// Kernel 3: combine 2 bf16 partials -> Q = 1/(1+sqrt(max(zsq+csq-2*cross,0))),
// row-normalize, column-sum (LDS reduce -> atomics).  32 rows/block, one
// wave per row, lane covers cols lane*8..+7.  (R10-proven)
// ---------------------------------------------------------------------------
__global__ __launch_bounds__(256) void k_q_norm(
    const unsigned short* __restrict__ parts,
    const float* __restrict__ zsq, const float* __restrict__ csq,
    float* __restrict__ Q, float* __restrict__ colsum)
{
    __shared__ float red[4][NCLUST];
    const int tid = threadIdx.x, w = tid >> 6, lane = tid & 63;
    const size_t PSTR = (size_t)M_ROWS * NCLUST;
    float ca[8] = {0, 0, 0, 0, 0, 0, 0, 0};
    const int rbase = blockIdx.x * 32;

    float cs[8];
    {
        float4 c0 = *(const float4*)(csq + lane * 8);
        float4 c1 = *(const float4*)(csq + lane * 8 + 4);
        cs[0] = c0.x; cs[1] = c0.y; cs[2] = c0.z; cs[3] = c0.w;
        cs[4] = c1.x; cs[5] = c1.y; cs[6] = c1.z; cs[7] = c1.w;
    }

    for (int rr = 0; rr < 8; ++rr) {
        const int row = rbase + w + rr * 4;
        const size_t off = (size_t)row * NCLUST + lane * 8;
        float x[8];
        {
            u16x8 v0 = *(const u16x8*)(parts + off);
            u16x8 v1 = *(const u16x8*)(parts + PSTR + off);
            #pragma unroll
            for (int k = 0; k < 8; ++k) x[k] = bf2f(v0[k]) + bf2f(v1[k]);
        }
        const float zr = zsq[row];
        float q[8];
        float sum = 0.f;
        #pragma unroll
        for (int k = 0; k < 8; ++k) {
            q[k] = 1.0f / (1.0f + sqrtf(fmaxf(zr + cs[k] - 2.0f * x[k], 0.0f)));
            sum += q[k];
        }
        #pragma unroll
        for (int o = 32; o; o >>= 1) sum += __shfl_down(sum, o);
        sum = __shfl(sum, 0);
        const float inv = 1.0f / sum;
        float4 q0, q1;
        q0.x = q[0] * inv; q0.y = q[1] * inv; q0.z = q[2] * inv; q0.w = q[3] * inv;
        q1.x = q[4] * inv; q1.y = q[5] * inv; q1.z = q[6] * inv; q1.w = q[7] * inv;
        *(float4*)(Q + off)     = q0;
        *(float4*)(Q + off + 4) = q1;
        ca[0] += q0.x; ca[1] += q0.y; ca[2] += q0.z; ca[3] += q0.w;
        ca[4] += q1.x; ca[5] += q1.y; ca[6] += q1.z; ca[7] += q1.w;
    }
    #pragma unroll
    for (int c = 0; c < 8; ++c) red[w][lane * 8 + c] = ca[c];
    __syncthreads();
    const float t0 = red[0][tid] + red[1][tid] + red[2][tid] + red[3][tid];
    const float t1 = red[0][tid + 256] + red[1][tid + 256] + red[2][tid + 256] + red[3][tid + 256];
    atomicAdd(&colsum[tid], t0);
    atomicAdd(&colsum[tid + 256], t1);
}

// ---------------------------------------------------------------------------
// Kernel 4: P = rownorm(Q^2 / colsum). One wave per row.  (R10-proven)
// ---------------------------------------------------------------------------
__global__ __launch_bounds__(256) void k_p(
    const float* __restrict__ Q, const float* __restrict__ colsum,
    float* __restrict__ P)
{
    const int w = threadIdx.x >> 6, lane = threadIdx.x & 63;
    const int row = blockIdx.x * 4 + w;
    const float* qp = Q + (size_t)row * NCLUST;
    float4 q0 = *(const float4*)(qp + lane * 4);
    float4 q1 = *(const float4*)(qp + 256 + lane * 4);
    float4 c0 = *(const float4*)(colsum + lane * 4);
    float4 c1 = *(const float4*)(colsum + 256 + lane * 4);
    float4 p0, p1;
    p0.x = q0.x * q0.x / c0.x; p0.y = q0.y * q0.y / c0.y;
    p0.z = q0.z * q0.z / c0.z; p0.w = q0.w * q0.w / c0.w;
    p1.x = q1.x * q1.x / c1.x; p1.y = q1.y * q1.y / c1.y;
    p1.z = q1.z * q1.z / c1.z; p1.w = q1.w * q1.w / c1.w;
    float s = p0.x + p0.y + p0.z + p0.w + p1.x + p1.y + p1.z + p1.w;
    #pragma unroll
    for (int off = 32; off; off >>= 1) s += __shfl_down(s, off);
    s = __shfl(s, 0);
    const float inv = 1.0f / s;
    p0.x *= inv; p0.y *= inv; p0.z *= inv; p0.w *= inv;
    p1.x *= inv; p1.y *= inv; p1.z *= inv; p1.w *= inv;
    float* op = P + (size_t)row * NCLUST;
    *(float4*)(op + lane * 4) = p0;
    *(float4*)(op + 256 + lane * 4) = p1;
}

extern "C" void kernel_launch(void* const* d_in, const int* in_sizes, int n_in,
                              void* d_out, int out_size, void* d_ws, size_t ws_size,
                              hipStream_t stream) {
    const float* z    = (const float*)d_in[0];
    const float* cent = (const float*)d_in[1];
    float* out = (float*)d_out;

    // workspace layout (~35 MiB; ws >= 69 MiB proven empirically in R3)
    char* ws = (char*)d_ws;
    unsigned char* zb = (unsigned char*)ws;                 // 16 MiB fp8
    unsigned char* cb = (unsigned char*)(ws + 16777216);    // 1 MiB fp8
    float* zsq    = (float*)(ws + 17825792);                // 32 KiB
    float* csq    = (float*)(ws + 17858560);                // 2 KiB
    float* colsum = (float*)(ws + 17860608);                // 2 KiB
    unsigned short* parts = (unsigned short*)(ws + 18874368); // 2 x 8 MiB bf16

    float* Q = out;                                  // (8192, 512)
    float* P = out + (size_t)M_ROWS * NCLUST;        // (8192, 512)

    k_convert<<<dim3((M_ROWS + NCLUST) / 4), dim3(256), 0, stream>>>(
        z, cent, zb, cb, zsq, csq, colsum);

    // grid 512 (XCD-aware decode inside) -> 2 blocks/CU, 4 waves each
    k_gemm_part<<<dim3(512), dim3(256), 0, stream>>>(zb, cb, parts);

    k_q_norm<<<dim3(M_ROWS / 32), dim3(256), 0, stream>>>(
        parts, zsq, csq, Q, colsum);

    k_p<<<dim3(M_ROWS / 4), dim3(256), 0, stream>>>(Q, colsum, P);
}